// Round 1
// baseline (123.522 us; speedup 1.0000x reference)
//
#include <hip/hip_runtime.h>

// Problem constants (from reference)
constexpr int BB  = 4;
constexpr int CC  = 128;
constexpr int HH  = 128;
constexpr int WW  = 128;
constexpr int HWW = HH * WW;   // 16384
constexpr int NV  = 32;        // votes per sphere point
constexpr int NP  = 4096;      // points per batch
constexpr int PT  = 16;        // points per block in gather kernel

// ---------------------------------------------------------------------------
// Kernel 1: transpose x [B][C][HW] -> xt [B][HW][C] (tiled, LDS, padded)
// ---------------------------------------------------------------------------
__global__ __launch_bounds__(256) void transpose_k(const float* __restrict__ x,
                                                   float* __restrict__ xt) {
  __shared__ float tile[32][33];  // +1 pad: conflict-free transposed read
  const int b   = blockIdx.z;
  const int hw0 = blockIdx.x * 32;
  const int c0  = blockIdx.y * 32;
  const int tx  = threadIdx.x;   // 0..31
  const int ty  = threadIdx.y;   // 0..7
  const float* xb  = x  + (size_t)b * CC * HWW;
  float*       xtb = xt + (size_t)b * HWW * CC;
#pragma unroll
  for (int j = 0; j < 4; ++j)
    tile[ty + j * 8][tx] = xb[(size_t)(c0 + ty + j * 8) * HWW + hw0 + tx];
  __syncthreads();
#pragma unroll
  for (int j = 0; j < 4; ++j)
    xtb[(size_t)(hw0 + ty + j * 8) * CC + c0 + tx] = tile[tx][ty + j * 8];
}

// ---------------------------------------------------------------------------
// Kernel 2: gather + weighted vote accumulation.
// Block: 128 threads = one per channel c. Each block handles PT points of one
// batch. idx/weight staged in LDS (idx premultiplied by C when transposed).
// Each vote read is a contiguous 512B row xt[b][hw][0..127] across the block.
// Output restaged through LDS so global stores are >=64B segments.
// XPOSED=false fallback reads x[b][c][hw] directly (correct but uncoalesced).
// ---------------------------------------------------------------------------
template <bool XPOSED>
__global__ __launch_bounds__(128) void gather_k(const float* __restrict__ xsrc,
                                                const int* __restrict__ vote_index,
                                                const float* __restrict__ vote_weight,
                                                const int* __restrict__ inds,
                                                float* __restrict__ out) {
  const int b  = blockIdx.y;
  const int p0 = blockIdx.x * PT;
  const int c  = threadIdx.x;  // 0..127

  __shared__ int   s_idx[PT][NV];
  __shared__ float s_w[PT][NV];

  for (int i = threadIdx.x; i < PT * NV; i += 128) {
    const int pp = i >> 5;        // NV == 32
    const int v  = i & (NV - 1);
    const int s  = inds[b * NP + p0 + pp];
    const int hw = vote_index[s * NV + v];
    s_idx[pp][v] = XPOSED ? hw * CC : hw;
    s_w[pp][v]   = vote_weight[s * NV + v];
  }
  __syncthreads();

  const float* xb = XPOSED ? (xsrc + (size_t)b * HWW * CC)
                           : (xsrc + ((size_t)b * CC + c) * HWW);

  float acc[PT];
#pragma unroll 1
  for (int pp = 0; pp < PT; ++pp) {
    float a = 0.f;
#pragma unroll
    for (int v = 0; v < NV; ++v) {
      const int off = s_idx[pp][v];
      const float xv = XPOSED ? xb[off + c] : xb[off];
      a += xv * s_w[pp][v];
    }
    acc[pp] = a;
  }
  __syncthreads();

  // Restage: acc[c][pp] -> LDS -> coalesced-ish stores (64B segments).
  __shared__ float s_out[128][PT + 1];  // +1 pad: stride 17 hits all banks
#pragma unroll
  for (int pp = 0; pp < PT; ++pp) s_out[c][pp] = acc[pp];
  __syncthreads();

  float* ob = out + (size_t)b * CC * NP + p0;
  for (int i = threadIdx.x; i < 128 * PT; i += 128) {
    const int cc = i / PT;
    const int p  = i % PT;
    ob[(size_t)cc * NP + p] = s_out[cc][p];
  }
}

// ---------------------------------------------------------------------------
extern "C" void kernel_launch(void* const* d_in, const int* in_sizes, int n_in,
                              void* d_out, int out_size, void* d_ws, size_t ws_size,
                              hipStream_t stream) {
  const float* x           = (const float*)d_in[0];
  const int*   vote_index  = (const int*)d_in[1];
  const float* vote_weight = (const float*)d_in[2];
  const int*   inds        = (const int*)d_in[3];
  float*       out         = (float*)d_out;

  const size_t xt_bytes = (size_t)BB * HWW * CC * sizeof(float);  // 32 MB
  if (ws_size >= xt_bytes) {
    float* xt = (float*)d_ws;
    dim3 tg(HWW / 32, CC / 32, BB);
    transpose_k<<<tg, dim3(32, 8), 0, stream>>>(x, xt);
    dim3 gg(NP / PT, BB);
    gather_k<true><<<gg, 128, 0, stream>>>(xt, vote_index, vote_weight, inds, out);
  } else {
    dim3 gg(NP / PT, BB);
    gather_k<false><<<gg, 128, 0, stream>>>(x, vote_index, vote_weight, inds, out);
  }
}

// Round 3
// 120.103 us; speedup vs baseline: 1.0285x; 1.0285x over previous
//
#include <hip/hip_runtime.h>

// Problem constants (from reference)
constexpr int BB  = 4;
constexpr int CC  = 128;
constexpr int HWW = 16384;     // H*W
constexpr int NV  = 32;        // votes per sphere point
constexpr int NP  = 4096;      // points per batch
constexpr int PT  = 8;         // points per gather block
constexpr int GT  = 128;       // gather block threads (4 subgroups x 32 lanes)

// ---------------------------------------------------------------------------
// Kernel 1: transpose x [B][C][HW] -> xt [B][HW][C] (tiled, LDS, padded)
// ---------------------------------------------------------------------------
__global__ __launch_bounds__(256) void transpose_k(const float* __restrict__ x,
                                                   float* __restrict__ xt) {
  __shared__ float tile[32][33];
  const int b   = blockIdx.z;
  const int hw0 = blockIdx.x * 32;
  const int c0  = blockIdx.y * 32;
  const int tx  = threadIdx.x;   // 0..31
  const int ty  = threadIdx.y;   // 0..7
  const float* xb  = x  + (size_t)b * CC * HWW;
  float*       xtb = xt + (size_t)b * HWW * CC;
#pragma unroll
  for (int j = 0; j < 4; ++j)
    tile[ty + j * 8][tx] = xb[(size_t)(c0 + ty + j * 8) * HWW + hw0 + tx];
  __syncthreads();
#pragma unroll
  for (int j = 0; j < 4; ++j)
    xtb[(size_t)(hw0 + ty + j * 8) * CC + c0 + tx] = tile[tx][ty + j * 8];
}

// ---------------------------------------------------------------------------
// Kernel 2: gather + weighted vote accumulation (float4 rows).
// Block: 128 threads = 4 subgroups of 32 lanes. Subgroup sg handles points
// {sg, sg+4} of this block's PT=8 points. Lane c4 owns channels 4*c4..4*c4+3.
// One vote row xt[b][hw][:] = 32 lanes x 16B = 512B in one instruction.
// Each lane accumulates all 32 votes for its (point, channel-quad): no
// cross-thread reduction. Output restaged via padded LDS -> float4 stores.
// ---------------------------------------------------------------------------
__global__ __launch_bounds__(GT, 4) void gather_k(const float* __restrict__ xt,
                                                  const int* __restrict__ vote_index,
                                                  const float* __restrict__ vote_weight,
                                                  const int* __restrict__ inds,
                                                  float* __restrict__ out) {
  const int b   = blockIdx.y;
  const int p0  = blockIdx.x * PT;
  const int tid = threadIdx.x;
  const int sg  = tid >> 5;     // 0..3
  const int c4  = tid & 31;     // channel quad

  __shared__ int   s_idx[PT][NV];
  __shared__ float s_w[PT][NV];

#pragma unroll
  for (int i = tid; i < PT * NV; i += GT) {
    const int pp = i >> 5;      // NV == 32
    const int v  = i & (NV - 1);
    const int s  = inds[b * NP + p0 + pp];
    s_idx[pp][v] = vote_index[s * NV + v] * CC;   // premultiplied row offset
    s_w[pp][v]   = vote_weight[s * NV + v];
  }
  __syncthreads();

  const float* xb = xt + (size_t)b * HWW * CC + (c4 << 2);

  float4 acc[2];
#pragma unroll
  for (int q = 0; q < 2; ++q) {
    const int pp = sg + q * 4;
    float4 a = {0.f, 0.f, 0.f, 0.f};
#pragma unroll
    for (int v = 0; v < NV; ++v) {
      const float  w  = s_w[pp][v];
      const float4 xv = *reinterpret_cast<const float4*>(xb + s_idx[pp][v]);
      a.x += xv.x * w;
      a.y += xv.y * w;
      a.z += xv.z * w;
      a.w += xv.w * w;
    }
    acc[q] = a;
  }
  __syncthreads();

  // Restage acc -> [C][PT] in LDS (pad to 12: write stride 48 -> 2-way max).
  __shared__ float s_out[CC][PT + 4];
#pragma unroll
  for (int q = 0; q < 2; ++q) {
    const int pp = sg + q * 4;
    s_out[(c4 << 2) + 0][pp] = acc[q].x;
    s_out[(c4 << 2) + 1][pp] = acc[q].y;
    s_out[(c4 << 2) + 2][pp] = acc[q].z;
    s_out[(c4 << 2) + 3][pp] = acc[q].w;
  }
  __syncthreads();

  // Each thread stores one channel row: 8 floats = 2 x float4.
  float* ob = out + ((size_t)b * CC + tid) * NP + p0;
  const float4 o0 = {s_out[tid][0], s_out[tid][1], s_out[tid][2], s_out[tid][3]};
  const float4 o1 = {s_out[tid][4], s_out[tid][5], s_out[tid][6], s_out[tid][7]};
  *reinterpret_cast<float4*>(ob)     = o0;
  *reinterpret_cast<float4*>(ob + 4) = o1;
}

// ---------------------------------------------------------------------------
// Fallback (no workspace): direct gather from x [B][C][HW], uncoalesced but
// correct. Only used if ws_size is too small for the 32 MB transpose buffer.
// ---------------------------------------------------------------------------
__global__ __launch_bounds__(128) void gather_fallback_k(const float* __restrict__ x,
                                                         const int* __restrict__ vote_index,
                                                         const float* __restrict__ vote_weight,
                                                         const int* __restrict__ inds,
                                                         float* __restrict__ out) {
  const int b = blockIdx.y;
  const int p = blockIdx.x;
  const int c = threadIdx.x;
  const int s = inds[b * NP + p];
  const float* xb = x + ((size_t)b * CC + c) * HWW;
  float a = 0.f;
  for (int v = 0; v < NV; ++v)
    a += xb[vote_index[s * NV + v]] * vote_weight[s * NV + v];
  out[((size_t)b * CC + c) * NP + p] = a;
}

// ---------------------------------------------------------------------------
extern "C" void kernel_launch(void* const* d_in, const int* in_sizes, int n_in,
                              void* d_out, int out_size, void* d_ws, size_t ws_size,
                              hipStream_t stream) {
  const float* x           = (const float*)d_in[0];
  const int*   vote_index  = (const int*)d_in[1];
  const float* vote_weight = (const float*)d_in[2];
  const int*   inds        = (const int*)d_in[3];
  float*       out         = (float*)d_out;

  const size_t xt_bytes = (size_t)BB * HWW * CC * sizeof(float);  // 32 MB
  if (ws_size >= xt_bytes) {
    float* xt = (float*)d_ws;
    dim3 tg(HWW / 32, CC / 32, BB);
    transpose_k<<<tg, dim3(32, 8), 0, stream>>>(x, xt);
    dim3 gg(NP / PT, BB);
    gather_k<<<gg, GT, 0, stream>>>(xt, vote_index, vote_weight, inds, out);
  } else {
    dim3 gg(NP, BB);
    gather_fallback_k<<<gg, CC, 0, stream>>>(x, vote_index, vote_weight, inds, out);
  }
}

// Round 4
// 102.073 us; speedup vs baseline: 1.2101x; 1.1766x over previous
//
#include <hip/hip_runtime.h>

typedef _Float16 half_t;
typedef _Float16 half2_t __attribute__((ext_vector_type(2)));
typedef _Float16 half8_t __attribute__((ext_vector_type(8)));

// Problem constants (from reference)
constexpr int BB  = 4;
constexpr int CC  = 128;
constexpr int HWW = 16384;     // H*W
constexpr int NV  = 32;        // votes per sphere point
constexpr int NP  = 4096;      // points per batch
constexpr int PT  = 8;         // points per gather block
constexpr int GT  = 128;       // gather threads: 8 subgroups x 16 lanes

// ---------------------------------------------------------------------------
// Kernel 1: transpose+convert x [B][C][HW] fp32 -> xt [B][HW][C] fp16.
// 64x64 tile in LDS (stride 65: 2-way max on both phases = free per m136).
// ---------------------------------------------------------------------------
__global__ __launch_bounds__(256) void transpose_h(const float* __restrict__ x,
                                                   half_t* __restrict__ xt) {
  __shared__ float tile[64][65];
  const int b   = blockIdx.z;
  const int hw0 = blockIdx.x * 64;
  const int c0  = blockIdx.y * 64;
  const int tx  = threadIdx.x & 63;   // hw within tile
  const int ty  = threadIdx.x >> 6;   // 0..3 c-phase
  const float* xb = x + (size_t)b * CC * HWW;
#pragma unroll
  for (int j = 0; j < 16; ++j)
    tile[ty + j * 4][tx] = xb[(size_t)(c0 + ty + j * 4) * HWW + hw0 + tx];
  __syncthreads();
  half_t* xtb = xt + (size_t)b * HWW * CC;
  const int cp = threadIdx.x & 31;    // half2 column (2 c values)
  const int r0 = threadIdx.x >> 5;    // 0..7 hw-phase
#pragma unroll
  for (int j = 0; j < 8; ++j) {
    const int hwr = r0 + j * 8;
    half2_t hv = {(half_t)tile[2 * cp][hwr], (half_t)tile[2 * cp + 1][hwr]};
    *reinterpret_cast<half2_t*>(xtb + (size_t)(hw0 + hwr) * CC + c0 + 2 * cp) = hv;
  }
}

// ---------------------------------------------------------------------------
// Kernel 2: gather + weighted vote accumulation from fp16 rows.
// 128 threads = 8 subgroups of 16 lanes; subgroup sg owns point p0+sg; lane
// c8 owns channels 8*c8..8*c8+7 (one 16B half8 load per vote). A 64-lane
// wave-instruction covers 4 rows = 1KB. fp32 accumulation. Output restaged
// via LDS [PT][CC+4] -> conflict-free reads -> 2x float4 stores per channel.
// ---------------------------------------------------------------------------
__global__ __launch_bounds__(GT, 4) void gather_h(const half_t* __restrict__ xt,
                                                  const int* __restrict__ vote_index,
                                                  const float* __restrict__ vote_weight,
                                                  const int* __restrict__ inds,
                                                  float* __restrict__ out) {
  const int b   = blockIdx.y;
  const int p0  = blockIdx.x * PT;
  const int tid = threadIdx.x;
  const int sg  = tid >> 4;   // 0..7 point
  const int c8  = tid & 15;   // channel octet

  __shared__ int   s_idx[PT][NV];
  __shared__ float s_w[PT][NV];
#pragma unroll
  for (int i = tid; i < PT * NV; i += GT) {
    const int pp = i >> 5;    // NV == 32
    const int v  = i & (NV - 1);
    const int s  = inds[b * NP + p0 + pp];
    s_idx[pp][v] = vote_index[s * NV + v] * CC;   // row offset in half units
    s_w[pp][v]   = vote_weight[s * NV + v];
  }
  __syncthreads();

  const half_t* xb = xt + (size_t)b * HWW * CC + c8 * 8;

  float acc[8] = {0.f, 0.f, 0.f, 0.f, 0.f, 0.f, 0.f, 0.f};
#pragma unroll
  for (int v = 0; v < NV; ++v) {
    const half8_t xv = *reinterpret_cast<const half8_t*>(xb + s_idx[sg][v]);
    const float   w  = s_w[sg][v];
#pragma unroll
    for (int k = 0; k < 8; ++k) acc[k] += (float)xv[k] * w;
  }
  __syncthreads();

  __shared__ float s_out[PT][CC + 4];
#pragma unroll
  for (int k = 0; k < 8; ++k) s_out[sg][c8 * 8 + k] = acc[k];
  __syncthreads();

  // Channel tid's PT=8 outputs, conflict-free LDS reads, 2 x float4 stores.
  float* ob = out + ((size_t)b * CC + tid) * NP + p0;
  const float4 o0 = {s_out[0][tid], s_out[1][tid], s_out[2][tid], s_out[3][tid]};
  const float4 o1 = {s_out[4][tid], s_out[5][tid], s_out[6][tid], s_out[7][tid]};
  *reinterpret_cast<float4*>(ob)     = o0;
  *reinterpret_cast<float4*>(ob + 4) = o1;
}

// ---------------------------------------------------------------------------
// Fallback (no workspace): direct fp32 gather, correct but uncoalesced.
// ---------------------------------------------------------------------------
__global__ __launch_bounds__(128) void gather_fallback_k(const float* __restrict__ x,
                                                         const int* __restrict__ vote_index,
                                                         const float* __restrict__ vote_weight,
                                                         const int* __restrict__ inds,
                                                         float* __restrict__ out) {
  const int b = blockIdx.y;
  const int p = blockIdx.x;
  const int c = threadIdx.x;
  const int s = inds[b * NP + p];
  const float* xb = x + ((size_t)b * CC + c) * HWW;
  float a = 0.f;
  for (int v = 0; v < NV; ++v)
    a += xb[vote_index[s * NV + v]] * vote_weight[s * NV + v];
  out[((size_t)b * CC + c) * NP + p] = a;
}

// ---------------------------------------------------------------------------
extern "C" void kernel_launch(void* const* d_in, const int* in_sizes, int n_in,
                              void* d_out, int out_size, void* d_ws, size_t ws_size,
                              hipStream_t stream) {
  const float* x           = (const float*)d_in[0];
  const int*   vote_index  = (const int*)d_in[1];
  const float* vote_weight = (const float*)d_in[2];
  const int*   inds        = (const int*)d_in[3];
  float*       out         = (float*)d_out;

  const size_t xt_bytes = (size_t)BB * HWW * CC * sizeof(half_t);  // 16 MB
  if (ws_size >= xt_bytes) {
    half_t* xt = (half_t*)d_ws;
    dim3 tg(HWW / 64, CC / 64, BB);
    transpose_h<<<tg, 256, 0, stream>>>(x, xt);
    dim3 gg(NP / PT, BB);
    gather_h<<<gg, GT, 0, stream>>>(xt, vote_index, vote_weight, inds, out);
  } else {
    dim3 gg(NP, BB);
    gather_fallback_k<<<gg, CC, 0, stream>>>(x, vote_index, vote_weight, inds, out);
  }
}